// Round 11
// baseline (243.322 us; speedup 1.0000x reference)
//
#include <hip/hip_runtime.h>

typedef int v4i __attribute__((ext_vector_type(4)));
typedef int v16i __attribute__((ext_vector_type(16)));

#define KDIM 2048
#define NDIM 2048

#define GLOAD16(g, l) __builtin_amdgcn_global_load_lds(                      \
    (const __attribute__((address_space(1))) void*)(g),                      \
    (__attribute__((address_space(3))) void*)(l), 16, 0, 0)

// ---------------- quant kernels ----------------

__device__ __forceinline__ int pack4q(float4 v, float s) {
  int a = __float2int_rn(v.x * s);
  int b = __float2int_rn(v.y * s);
  int c = __float2int_rn(v.z * s);
  int d = __float2int_rn(v.w * s);
  a = max(-128, min(127, a)); b = max(-128, min(127, b));
  c = max(-128, min(127, c)); d = max(-128, min(127, d));
  return (a & 0xff) | ((b & 0xff) << 8) | ((c & 0xff) << 16) | ((d & 0xff) << 24);
}

__global__ __launch_bounds__(256) void quant_rows(const float* __restrict__ x,
                                                  signed char* __restrict__ q,
                                                  float* __restrict__ rscale) {
  const int row = blockIdx.x;
  const float4* xr = (const float4*)(x + (size_t)row * KDIM);
  float4 v0 = xr[threadIdx.x];
  float4 v1 = xr[256 + threadIdx.x];
  float m = fmaxf(fmaxf(fabsf(v0.x), fabsf(v0.y)), fmaxf(fabsf(v0.z), fabsf(v0.w)));
  m = fmaxf(m, fmaxf(fmaxf(fabsf(v1.x), fabsf(v1.y)), fmaxf(fabsf(v1.z), fabsf(v1.w))));
  #pragma unroll
  for (int off = 32; off > 0; off >>= 1) m = fmaxf(m, __shfl_xor(m, off));
  __shared__ float red[4];
  if ((threadIdx.x & 63) == 0) red[threadIdx.x >> 6] = m;
  __syncthreads();
  float xmax = fmaxf(fmaxf(red[0], red[1]), fmaxf(red[2], red[3]));
  xmax = fmaxf(xmax, 1e-5f);
  const float scale = 127.0f / xmax;
  int* qr = (int*)(q + (size_t)row * KDIM);
  qr[threadIdx.x] = pack4q(v0, scale);
  qr[256 + threadIdx.x] = pack4q(v1, scale);
  if (threadIdx.x == 0) rscale[row] = xmax * (1.0f / 127.0f);
}

__global__ __launch_bounds__(256) void quant_w(const float* __restrict__ W,
                                               signed char* __restrict__ Wq) {
  const int i = blockIdx.x * 256 + threadIdx.x;
  float4 v = ((const float4*)W)[i];
  int a = (int)v.x, b = (int)v.y, c = (int)v.z, d = (int)v.w;
  ((int*)Wq)[i] = (a & 0xff) | ((b << 8) & 0xff00) | ((c << 16) & 0xff0000) | (d << 24);
}

// ---- 256x256 8-wave i8 GEMM, 4-ring + counted vmcnt, MFMA 32x32x32 (round-11) ----
// Round-11: only change vs R10 = MFMA shape 16x16x64 -> 32x32x32 (half the
// instruction count per K-byte, 4404 vs 3944 TOPS ubench). Tests the
// per-instruction-overhead hypothesis: 6 schedules all measured ~3262 cyc/tile
// = 64 inst x (20.4 pipe + ~30 overhead). If overhead is per-inst, halving the
// count cuts ~1000 cyc/tile.
// Wave-tile 128x64 = 4m x 2n frags of 32x32; per tile 16 MFMA, 12 ds_read_b128.
// Staging/ladder/swizzle identical to R10 (LDS layout unchanged, 0-conflict).
// ds_read: row = ...+(lane&31), logical k-slot = 2*kk+(lane>>5); phys slot =
// logical ^ ((row>>1)&3) = logical ^ ((lane>>1)&3). Quarter-wave covers the 8
// bank-period positions 2-way (free).

#define VM8 asm volatile("s_waitcnt vmcnt(8)" ::: "memory")
#define VM4 asm volatile("s_waitcnt vmcnt(4)" ::: "memory")
#define VM0 asm volatile("s_waitcnt vmcnt(0)" ::: "memory")
#define VMNONE

#define STAGE_A(U, T)                                                        \
  GLOAD16(sa + (T) * 64, lds + (U) * 32768 + dstw);                          \
  GLOAD16(sa + (T) * 64 + 128 * KDIM, lds + (U) * 32768 + 8192 + dstw);
#define STAGE_B(U, T)                                                        \
  GLOAD16(sb + (T) * 64, lds + (U) * 32768 + 16384 + dstw);                  \
  GLOAD16(sb + (T) * 64 + 128 * KDIM, lds + (U) * 32768 + 24576 + dstw);

// one output frag (m,n): accumulate kk=0 then kk=1
#define MF2(m, n, A0, A1)                                                    \
  acc[m][n] = __builtin_amdgcn_mfma_i32_32x32x32_i8((A0), bf##n##0, acc[m][n], 0, 0, 0); \
  acc[m][n] = __builtin_amdgcn_mfma_i32_32x32x32_i8((A1), bf##n##1, acc[m][n], 0, 0, 0);

#define KTILE(U, T, DOSTAGE, VMEND)                                          \
  {                                                                          \
    /* ---- phase A: read m0-1 A-frags + all B-frags; MFMA m0-1 ---- */      \
    v4i a00 = *(const v4i*)(lds + (U) * 32768 + aRow + rs0);                 \
    v4i a01 = *(const v4i*)(lds + (U) * 32768 + aRow + rs1);                 \
    v4i a10 = *(const v4i*)(lds + (U) * 32768 + aRow + 2048 + rs0);          \
    v4i a11 = *(const v4i*)(lds + (U) * 32768 + aRow + 2048 + rs1);          \
    v4i bf00 = *(const v4i*)(lds + (U) * 32768 + bRow + rs0);                \
    v4i bf01 = *(const v4i*)(lds + (U) * 32768 + bRow + rs1);                \
    v4i bf10 = *(const v4i*)(lds + (U) * 32768 + bRow + 2048 + rs0);         \
    v4i bf11 = *(const v4i*)(lds + (U) * 32768 + bRow + 2048 + rs1);         \
    if (DOSTAGE) { STAGE_A((((U) + 3) & 3), (T) + 3) }                       \
    __builtin_amdgcn_sched_barrier(0);                                       \
    __builtin_amdgcn_s_barrier();                                            \
    asm volatile("s_waitcnt lgkmcnt(0)" ::: "memory");                       \
    __builtin_amdgcn_sched_barrier(0);                                       \
    __builtin_amdgcn_s_setprio(1);                                           \
    MF2(0, 0, a00, a01) MF2(0, 1, a00, a01)                                  \
    MF2(1, 0, a10, a11) MF2(1, 1, a10, a11)                                  \
    __builtin_amdgcn_s_setprio(0);                                           \
    __builtin_amdgcn_sched_barrier(0);                                       \
    __builtin_amdgcn_s_barrier();                                            \
    /* ---- phase B: read m2-3 A-frags (B reused in regs); MFMA m2-3 ---- */ \
    v4i a20 = *(const v4i*)(lds + (U) * 32768 + aRow + 4096 + rs0);          \
    v4i a21 = *(const v4i*)(lds + (U) * 32768 + aRow + 4096 + rs1);          \
    v4i a30 = *(const v4i*)(lds + (U) * 32768 + aRow + 6144 + rs0);          \
    v4i a31 = *(const v4i*)(lds + (U) * 32768 + aRow + 6144 + rs1);          \
    if (DOSTAGE) { STAGE_B((((U) + 3) & 3), (T) + 3) }                       \
    __builtin_amdgcn_sched_barrier(0);                                       \
    __builtin_amdgcn_s_barrier();                                            \
    asm volatile("s_waitcnt lgkmcnt(0)" ::: "memory");                       \
    __builtin_amdgcn_sched_barrier(0);                                       \
    __builtin_amdgcn_s_setprio(1);                                           \
    MF2(2, 0, a20, a21) MF2(2, 1, a20, a21)                                  \
    MF2(3, 0, a30, a31) MF2(3, 1, a30, a31)                                  \
    __builtin_amdgcn_s_setprio(0);                                           \
    __builtin_amdgcn_sched_barrier(0);                                       \
    VMEND;                                                                   \
    __builtin_amdgcn_s_barrier();                                            \
  }

__global__ __launch_bounds__(512, 2) void gemm_i8(const signed char* __restrict__ A,
                                                  const signed char* __restrict__ B,
                                                  const float* __restrict__ rscale,
                                                  float* __restrict__ C) {
  __shared__ __align__(16) signed char lds[131072];
  const int bid = blockIdx.x;
  const int lid = (bid & 7) * 128 + (bid >> 3);  // bijective XCD swizzle (1024 % 8 == 0)
  const int bm = lid >> 3;                       // 128 row tiles
  const int bn = lid & 7;                        // 8 col tiles
  const int tid = threadIdx.x;
  const int wid = tid >> 6;
  const int lane = tid & 63;
  const int wr = wid >> 2, wc = wid & 3;         // wave-tile 128 rows x 64 cols

  // staging (identical to R10): thread covers row = wid*16 + (lane>>2) per
  // 128-row half; dest slot = lane&3 (HW linear).
  // source logical slot = (lane&3) ^ ((row>>1)&3) = (lane&3) ^ ((lane>>3)&3).
  const int srow = wid * 16 + (lane >> 2);
  const int scol = (((lane & 3) ^ ((lane >> 3) & 3)) << 4);
  const signed char* sa = A + (size_t)(bm * 256 + srow) * KDIM + scol;
  const signed char* sb = B + (size_t)(bn * 256 + srow) * KDIM + scol;
  const int dstw = wid << 10;  // wave-uniform LDS chunk; HW adds lane*16

  // ds_read bases: row = ...+(lane&31); swizzle sw = (lane>>1)&3;
  // k-slot(kk) = 2*kk + (lane>>5) -> phys slot = (k-slot ^ sw).
  const int sw = (lane >> 1) & 3;
  const int rs0 = (((lane >> 5) ^ sw) << 4);          // kk = 0
  const int rs1 = (((2 | (lane >> 5)) ^ sw) << 4);    // kk = 1
  const int aRow = (wr * 128 + (lane & 31)) * 64;     // + m*2048 per m-frag
  const int bRow = 16384 + (wc * 64 + (lane & 31)) * 64;  // + n*2048 per n-frag

  v16i acc[4][2] = {};

  // prologue: stage S(0), S(1), S(2); W(0)
  STAGE_A(0, 0) STAGE_B(0, 0)
  STAGE_A(1, 1) STAGE_B(1, 1)
  STAGE_A(2, 2) STAGE_B(2, 2)
  VM8;
  __builtin_amdgcn_s_barrier();

  for (int ti = 0; ti < 7; ++ti) {
    const int t = ti * 4;
    KTILE(0, t + 0, 1, VM8)
    KTILE(1, t + 1, 1, VM8)
    KTILE(2, t + 2, 1, VM8)
    KTILE(3, t + 3, 1, VM8)
  }
  KTILE(0, 28, 1, VM8)    // stages S(31)
  KTILE(1, 29, 0, VM4)    // W(30)
  KTILE(2, 30, 0, VM0)    // W(31)
  KTILE(3, 31, 0, VMNONE)

  // epilogue: 32x32 C/D layout: col = lane&31, row = (reg&3) + 8*(reg>>2) + 4*(lane>>5)
  const int col0 = bn * 256 + wc * 64 + (lane & 31);
  const int rb = bm * 256 + wr * 128 + ((lane >> 5) << 2);
  #pragma unroll
  for (int m = 0; m < 4; ++m) {
    #pragma unroll
    for (int r = 0; r < 16; ++r) {
      const int row = rb + m * 32 + (r & 3) + ((r >> 2) << 3);
      const float s = rscale[row];
      float* crow = C + (size_t)row * NDIM + col0;
      crow[0]  = (float)acc[m][0][r] * s;
      crow[32] = (float)acc[m][1][r] * s;
    }
  }
}

extern "C" void kernel_launch(void* const* d_in, const int* in_sizes, int n_in,
                              void* d_out, int out_size, void* d_ws, size_t ws_size,
                              hipStream_t stream) {
  const float* x = (const float*)d_in[0];
  const float* W = (const float*)d_in[1];
  float* out = (float*)d_out;
  const int M = in_sizes[0] / KDIM;  // 32768

  signed char* q = (signed char*)d_ws;                       // M*K   = 64 MB
  signed char* Wq = q + (size_t)M * KDIM;                    // N*K   =  4 MB
  float* rscale = (float*)(Wq + (size_t)NDIM * KDIM);        // M*4   = 128 KB

  quant_rows<<<M, 256, 0, stream>>>(x, q, rscale);
  quant_w<<<(NDIM * KDIM / 4) / 256, 256, 0, stream>>>(W, Wq);
  gemm_i8<<<(M / 256) * (NDIM / 256), 512, 0, stream>>>(q, Wq, rscale, out);
}